// Round 9
// baseline (103.859 us; speedup 1.0000x reference)
//
#include <hip/hip_runtime.h>

#define BATCH 65536
#define NSPL  64
#define CDIM  64
#define TDIM  68          // CDIM + DEGREE + 1
#define QI    67          // degree-0 intervals
#define RTN   67          // region-table entries per spline

#define TCOLS 16          // splines per block: full 64B line per row
#define TROWS 256         // rows per block (4 rows/lane/column)
#define NTHR  256
#define PITCH 257         // 257 % 32 == 1: compute-phase stride-1 reads free

// ============================================================================
// Sorted-region formulation (R8, proven): S(x) is piecewise-cubic with
// breakpoints at the sorted knot values; region index = #{j: x >= t_j} over
// the ORIGINAL knots (count is order-independent); prep sums active Q_i per
// region (fp64) -> RT[spline][m-1] float4; m=0/68 -> 0.
// R8 lesson (inferred from kernel falling under the 44us poison-fills in
// top-5, headline arithmetic): main ~35-40us vs 7.5us VALU floor -> the
// per-column 68-knot s_load stream stalls on lgkmcnt (SGPR budget can't hold
// the table; R5 disease again). R9: knots prefetched into 2 lane-resident
// VGPRs per column (all 4 columns up front, one vmcnt drain), count loop fed
// by v_readlane (pure VALU, zero latency), 4 rows/lane for 8 independent
// cmp+addc per knot. Hot loop touches NO memory pipe.
// ============================================================================

__global__ __launch_bounds__(128) void prep(const float* __restrict__ T,
                                            const float* __restrict__ C,
                                            float4* __restrict__ RT) {
    __shared__ double  td[TDIM];
    __shared__ double  cd[CDIM];
    __shared__ double  R1[QI], R2[TDIM - 2], R3[TDIM - 3];
    __shared__ double4 Qd[QI];
    __shared__ float   tf[TDIM];
    __shared__ float   srt[TDIM];

    const int s = blockIdx.x;
    const int t = threadIdx.x;

    if (t < TDIM) { float v = T[s * TDIM + t]; tf[t] = v; td[t] = (double)v; }
    if (t >= 64 && t < 64 + CDIM) cd[t - 64] = (double)C[s * CDIM + t - 64];
    __syncthreads();

    // Safe reciprocals (0/0 := 0; fp64 diff is 0 iff fp32 values equal).
    if (t < TDIM - 1) { double d = td[t + 1] - td[t]; R1[t] = (d == 0.0) ? 0.0 : 1.0 / d; }
    if (t < TDIM - 2) { double d = td[t + 2] - td[t]; R2[t] = (d == 0.0) ? 0.0 : 1.0 / d; }
    if (t < TDIM - 3) { double d = td[t + 3] - td[t]; R3[t] = (d == 0.0) ? 0.0 : 1.0 / d; }
    // Rank-sort the 68 knots (ties broken by index -> deterministic).
    if (t < TDIM) {
        float v = tf[t];
        int r = 0;
        for (int k = 0; k < TDIM; ++k)
            r += (tf[k] < v) || (tf[k] == v && k < t);
        srt[r] = v;
    }
    __syncthreads();

    // Expand Q_i: cubic for interval i, sum over <=8 Cox-de Boor lattice paths.
    if (t < QI) {
        const int i = t;
        double q0 = 0, q1 = 0, q2 = 0, q3 = 0;
        for (int j = i - 3; j <= i; ++j) {
            if (j < 0 || j > CDIM - 1) continue;
            double cj = cd[j];
            for (int b2 = 0; b2 < 2; ++b2) {
                int m2 = j + b2;
                double D3 = R3[j + b2];
                double p3 = b2 ? -D3 : D3;
                double r3 = b2 ? D3 * td[j + 4] : -D3 * td[j];
                for (int b1 = 0; b1 < 2; ++b1) {
                    int m1 = m2 + b1;
                    double D2 = R2[m2 + b1];
                    double p2 = b1 ? -D2 : D2;
                    double r2 = b1 ? D2 * td[m2 + 3] : -D2 * td[m2];
                    for (int b0 = 0; b0 < 2; ++b0) {
                        if (m1 + b0 != i) continue;   // path must end at interval i
                        double D1 = R1[m1 + b0];
                        double p1 = b0 ? -D1 : D1;
                        double r1 = b0 ? D1 * td[m1 + 2] : -D1 * td[m1];
                        double a2 = p3 * p2, a1 = p3 * r2 + r3 * p2, a0 = r3 * r2;
                        q3 += cj * (a2 * p1);
                        q2 += cj * (a2 * r1 + a1 * p1);
                        q1 += cj * (a1 * r1 + a0 * p1);
                        q0 += cj * (a0 * r1);
                    }
                }
            }
        }
        double4 q; q.x = q0; q.y = q1; q.z = q2; q.w = q3;
        Qd[i] = q;
    }
    __syncthreads();

    // Region sums: for m = t in 1..67, x* = srt[m-1]; active i <=> same fp32
    // predicates as the reference. Coefficient-wise fp64 sum -> fp32 cubic.
    if (t >= 1 && t <= RTN) {
        const float xs = srt[t - 1];
        double a0 = 0, a1 = 0, a2 = 0, a3 = 0;
        for (int i = 0; i < QI; ++i) {
            if (tf[i] <= xs && xs < tf[i + 1]) {
                double4 q = Qd[i];
                a0 += q.x; a1 += q.y; a2 += q.z; a3 += q.w;
            }
        }
        float4 v; v.x = (float)a0; v.y = (float)a1; v.z = (float)a2; v.w = (float)a3;
        RT[s * RTN + (t - 1)] = v;
    }
}

static __device__ __forceinline__ float rdlane(float v, int l) {
    return __builtin_bit_cast(float, __builtin_amdgcn_readlane(__builtin_bit_cast(int, v), l));
}

__global__ __launch_bounds__(NTHR) void bspline_main(const float* __restrict__ X,
                                                     const float* __restrict__ T,
                                                     const float4* __restrict__ RT,
                                                     float* __restrict__ O) {
    __shared__ float4 rt[TCOLS * RTN];    // 17,152 B: region cubics for 16 splines
    __shared__ float  xl[TCOLS * PITCH];  // 16,448 B: x tile [col][row]; reused for out

    const int tid  = threadIdx.x;
    const int lane = tid & 63;
    const int w    = tid >> 6;
    const int r0   = blockIdx.x * TROWS;
    const int s0   = blockIdx.y * TCOLS;

    // Stage region tables: contiguous copy (global layout == LDS layout).
    for (int e = tid; e < TCOLS * RTN; e += NTHR)
        rt[e] = RT[s0 * RTN + e];

    // Stage X tile: coalesced global (4 full 64B lines per wave-instr).
    #pragma unroll
    for (int it = 0; it < TROWS * TCOLS / NTHR; ++it) {   // 16 iters
        int e = tid + it * NTHR;
        int r = e >> 4, c = e & 15;
        xl[c * PITCH + r] = X[(r0 + r) * NSPL + s0 + c];
    }

    // Prefetch all 4 columns' knots into lane-resident VGPRs (8 loads, one
    // drain): kA[cc] lane j = t_j (j=0..63); kB[cc] lanes 0..3 = t_64..t_67.
    float kA[4], kB[4];
    #pragma unroll
    for (int cc = 0; cc < 4; ++cc) {
        const int sp = s0 + w * 4 + cc;
        kA[cc] = T[sp * TDIM + lane];
        kB[cc] = T[sp * TDIM + 64 + (lane & 3)];
    }
    __syncthreads();

    // Wave w owns columns 4w..4w+3 exclusively; 4 rows per lane per column.
    #pragma unroll 1
    for (int cc = 0; cc < 4; ++cc) {
        const int c = w * 4 + cc;
        float* xc = xl + c * PITCH + lane;

        float x0 = xc[0], x1 = xc[64], x2 = xc[128], x3 = xc[192];  // stride-1: free
        unsigned n0 = 0, n1 = 0, n2 = 0, n3 = 0;

        // Hot loop: 1 v_readlane + 8 cmp/addc per knot; ZERO memory ops.
        #pragma unroll
        for (int j = 0; j < 64; ++j) {
            float tj = rdlane(kA[cc], j);
            n0 += (x0 >= tj); n1 += (x1 >= tj);
            n2 += (x2 >= tj); n3 += (x3 >= tj);
        }
        #pragma unroll
        for (int j = 0; j < 4; ++j) {
            float tj = rdlane(kB[cc], j);
            n0 += (x0 >= tj); n1 += (x1 >= tj);
            n2 += (x2 >= tj); n3 += (x3 >= tj);
        }

        // Region m = n; table entry m-1 for m in [1,67]; m=0/68 -> 0.
        const int m0 = (n0 < 1u ? 0 : (n0 > 67u ? 66 : (int)n0 - 1));
        const int m1 = (n1 < 1u ? 0 : (n1 > 67u ? 66 : (int)n1 - 1));
        const int m2 = (n2 < 1u ? 0 : (n2 > 67u ? 66 : (int)n2 - 1));
        const int m3 = (n3 < 1u ? 0 : (n3 > 67u ? 66 : (int)n3 - 1));
        float4 p0 = rt[c * RTN + m0];        // divergent ds_read_b128 gathers
        float4 p1 = rt[c * RTN + m1];
        float4 p2 = rt[c * RTN + m2];
        float4 p3 = rt[c * RTN + m3];
        float y0 = fmaf(fmaf(fmaf(p0.w, x0, p0.z), x0, p0.y), x0, p0.x);
        float y1 = fmaf(fmaf(fmaf(p1.w, x1, p1.z), x1, p1.y), x1, p1.x);
        float y2 = fmaf(fmaf(fmaf(p2.w, x2, p2.z), x2, p2.y), x2, p2.x);
        float y3 = fmaf(fmaf(fmaf(p3.w, x3, p3.z), x3, p3.y), x3, p3.x);
        y0 = (n0 - 1u < 67u) ? y0 : 0.f;     // outside all knots -> 0
        y1 = (n1 - 1u < 67u) ? y1 : 0.f;
        y2 = (n2 - 1u < 67u) ? y2 : 0.f;
        y3 = (n3 - 1u < 67u) ? y3 : 0.f;

        // In-place write-back: column c touched only by wave w; all x reads
        // for this column happened above in wave lockstep.
        xc[0] = y0; xc[64] = y1; xc[128] = y2; xc[192] = y3;
    }
    __syncthreads();

    // Write out: full 64B lines per row.
    #pragma unroll
    for (int it = 0; it < TROWS * TCOLS / NTHR; ++it) {
        int e = tid + it * NTHR;
        int r = e >> 4, c = e & 15;
        O[(r0 + r) * NSPL + s0 + c] = xl[c * PITCH + r];
    }
}

extern "C" void kernel_launch(void* const* d_in, const int* in_sizes, int n_in,
                              void* d_out, int out_size, void* d_ws, size_t ws_size,
                              hipStream_t stream) {
    const float* X = (const float*)d_in[0];  // [65536, 64]
    const float* T = (const float*)d_in[1];  // [64, 68]
    const float* C = (const float*)d_in[2];  // [64, 64]
    float* O = (float*)d_out;                // [65536, 64]
    float4* RT = (float4*)d_ws;              // 64*67 float4 = 68,608 B

    prep<<<NSPL, 128, 0, stream>>>(T, C, RT);
    dim3 grid(BATCH / TROWS, NSPL / TCOLS);  // (256, 4) = 1024 blocks = 4/CU, no tail
    bspline_main<<<grid, NTHR, 0, stream>>>(X, T, RT, O);
}

// Round 10
// 100.791 us; speedup vs baseline: 1.0304x; 1.0304x over previous
//
#include <hip/hip_runtime.h>

#define BATCH 65536
#define NSPL  64
#define CDIM  64
#define TDIM  68          // CDIM + DEGREE + 1
#define QI    67          // degree-0 intervals
#define RTN   67          // region-table entries per spline

#define TCOLS 16          // splines per block: full 64B line per row
#define TROWS 128         // rows per block (2 rows/lane/column)
#define NTHR  256
#define PITCH 129         // 129 % 32 == 1: compute-phase stride-1 reads free

// ============================================================================
// Sorted-region formulation (R8, proven): S(x) is piecewise-cubic with
// breakpoints at the sorted knot values; region index m = #{j: x >= t_j} over
// the ORIGINAL knots (order-independent count); prep sums active Q_i per
// region (fp64) -> RT[spline][m-1] float4; m=0/68 -> 0.
// R9 null result: s_load feed (R8) == readlane feed (R9) -> table feed is not
// the constraint. Remaining suspects shared by R8/R9: (1) divergent
// ds_read_b128 gather (random m -> 4-bank-group collisions, single LDS pipe
// per CU), (2) 16-24 waves/CU occupancy. R10: gather RT straight from global
// (1KB/spline -> L1-resident, pipelined VMEM path, zero LDS-pipe cost), drop
// rt staging, LDS = 8.3KB x-tile only -> 8 blocks/CU (wave-capped, 32
// waves/CU). Knots via s_load (simplest of the two proven-equal feeds).
// ============================================================================

__global__ __launch_bounds__(128) void prep(const float* __restrict__ T,
                                            const float* __restrict__ C,
                                            float4* __restrict__ RT) {
    __shared__ double  td[TDIM];
    __shared__ double  cd[CDIM];
    __shared__ double  R1[QI], R2[TDIM - 2], R3[TDIM - 3];
    __shared__ double4 Qd[QI];
    __shared__ float   tf[TDIM];
    __shared__ float   srt[TDIM];

    const int s = blockIdx.x;
    const int t = threadIdx.x;

    if (t < TDIM) { float v = T[s * TDIM + t]; tf[t] = v; td[t] = (double)v; }
    if (t >= 64 && t < 64 + CDIM) cd[t - 64] = (double)C[s * CDIM + t - 64];
    __syncthreads();

    // Safe reciprocals (0/0 := 0; fp64 diff is 0 iff fp32 values equal).
    if (t < TDIM - 1) { double d = td[t + 1] - td[t]; R1[t] = (d == 0.0) ? 0.0 : 1.0 / d; }
    if (t < TDIM - 2) { double d = td[t + 2] - td[t]; R2[t] = (d == 0.0) ? 0.0 : 1.0 / d; }
    if (t < TDIM - 3) { double d = td[t + 3] - td[t]; R3[t] = (d == 0.0) ? 0.0 : 1.0 / d; }
    // Rank-sort the 68 knots (ties broken by index -> deterministic).
    if (t < TDIM) {
        float v = tf[t];
        int r = 0;
        for (int k = 0; k < TDIM; ++k)
            r += (tf[k] < v) || (tf[k] == v && k < t);
        srt[r] = v;
    }
    __syncthreads();

    // Expand Q_i: cubic for interval i, sum over <=8 Cox-de Boor lattice paths.
    if (t < QI) {
        const int i = t;
        double q0 = 0, q1 = 0, q2 = 0, q3 = 0;
        for (int j = i - 3; j <= i; ++j) {
            if (j < 0 || j > CDIM - 1) continue;
            double cj = cd[j];
            for (int b2 = 0; b2 < 2; ++b2) {
                int m2 = j + b2;
                double D3 = R3[j + b2];
                double p3 = b2 ? -D3 : D3;
                double r3 = b2 ? D3 * td[j + 4] : -D3 * td[j];
                for (int b1 = 0; b1 < 2; ++b1) {
                    int m1 = m2 + b1;
                    double D2 = R2[m2 + b1];
                    double p2 = b1 ? -D2 : D2;
                    double r2 = b1 ? D2 * td[m2 + 3] : -D2 * td[m2];
                    for (int b0 = 0; b0 < 2; ++b0) {
                        if (m1 + b0 != i) continue;   // path must end at interval i
                        double D1 = R1[m1 + b0];
                        double p1 = b0 ? -D1 : D1;
                        double r1 = b0 ? D1 * td[m1 + 2] : -D1 * td[m1];
                        double a2 = p3 * p2, a1 = p3 * r2 + r3 * p2, a0 = r3 * r2;
                        q3 += cj * (a2 * p1);
                        q2 += cj * (a2 * r1 + a1 * p1);
                        q1 += cj * (a1 * r1 + a0 * p1);
                        q0 += cj * (a0 * r1);
                    }
                }
            }
        }
        double4 q; q.x = q0; q.y = q1; q.z = q2; q.w = q3;
        Qd[i] = q;
    }
    __syncthreads();

    // Region sums: for m = t in 1..67, x* = srt[m-1]; active i <=> same fp32
    // predicates as the reference. Coefficient-wise fp64 sum -> fp32 cubic.
    if (t >= 1 && t <= RTN) {
        const float xs = srt[t - 1];
        double a0 = 0, a1 = 0, a2 = 0, a3 = 0;
        for (int i = 0; i < QI; ++i) {
            if (tf[i] <= xs && xs < tf[i + 1]) {
                double4 q = Qd[i];
                a0 += q.x; a1 += q.y; a2 += q.z; a3 += q.w;
            }
        }
        float4 v; v.x = (float)a0; v.y = (float)a1; v.z = (float)a2; v.w = (float)a3;
        RT[s * RTN + (t - 1)] = v;
    }
}

__global__ __launch_bounds__(NTHR) void bspline_main(const float* __restrict__ X,
                                                     const float* __restrict__ T,
                                                     const float4* __restrict__ RT,
                                                     float* __restrict__ O) {
    __shared__ float xl[TCOLS * PITCH];   // 8,256 B: x tile [col][row]; reused for out

    const int tid  = threadIdx.x;
    const int lane = tid & 63;
    const int w    = tid >> 6;
    const int r0   = blockIdx.x * TROWS;
    const int s0   = blockIdx.y * TCOLS;

    // Stage X tile: coalesced global (4 full 64B lines per wave-instr);
    // LDS banks (c*129 + r) % 32 = (c + r) % 32 -> <=4-way (r spans 4): cheap.
    #pragma unroll
    for (int it = 0; it < TROWS * TCOLS / NTHR; ++it) {   // 8 iters
        int e = tid + it * NTHR;
        int r = e >> 4, c = e & 15;
        xl[c * PITCH + r] = X[(r0 + r) * NSPL + s0 + c];
    }
    __syncthreads();

    // Wave w owns columns 4w..4w+3 exclusively; 2 rows per lane per column.
    #pragma unroll 1
    for (int cc = 0; cc < 4; ++cc) {
        const int c  = w * 4 + cc;
        const int sp = __builtin_amdgcn_readfirstlane(s0 + c);
        const float* kn = T + sp * TDIM;          // wave-uniform -> s_load stream

        float* xc = xl + c * PITCH + lane;
        const float x0 = xc[0];                   // stride-1: conflict-free
        const float x1 = xc[64];
        unsigned n0 = 0, n1 = 0;
        #pragma unroll
        for (int j = 0; j < TDIM; ++j) {
            float tj = kn[j];                     // uniform scalar (s_load)
            n0 += (x0 >= tj);                     // v_cmp + v_addc
            n1 += (x1 >= tj);
        }
        // Region m = n; table entry m-1 for m in [1,67]; m=0/68 -> 0.
        unsigned i0 = n0 - 1u; i0 = (i0 > 66u) ? 66u : i0;   // wrap(n=0)->66 too
        unsigned i1 = n1 - 1u; i1 = (i1 > 66u) ? 66u : i1;
        // Gather straight from global: ~1KB/spline -> L1-resident, VMEM path,
        // zero LDS-pipe cost (this replaces R8/R9's conflicted LDS gather).
        const float4* rts = RT + sp * RTN;
        float4 p0 = rts[i0];
        float4 p1 = rts[i1];
        float y0 = fmaf(fmaf(fmaf(p0.w, x0, p0.z), x0, p0.y), x0, p0.x);
        float y1 = fmaf(fmaf(fmaf(p1.w, x1, p1.z), x1, p1.y), x1, p1.x);
        y0 = (n0 - 1u < 67u) ? y0 : 0.f;          // m=0 or m=68 -> outside knots
        y1 = (n1 - 1u < 67u) ? y1 : 0.f;
        // In-place write-back: column c touched only by wave w; x reads done.
        xc[0]  = y0;
        xc[64] = y1;
    }
    __syncthreads();

    // Write out: full 64B lines per row.
    #pragma unroll
    for (int it = 0; it < TROWS * TCOLS / NTHR; ++it) {
        int e = tid + it * NTHR;
        int r = e >> 4, c = e & 15;
        O[(r0 + r) * NSPL + s0 + c] = xl[c * PITCH + r];
    }
}

extern "C" void kernel_launch(void* const* d_in, const int* in_sizes, int n_in,
                              void* d_out, int out_size, void* d_ws, size_t ws_size,
                              hipStream_t stream) {
    const float* X = (const float*)d_in[0];  // [65536, 64]
    const float* T = (const float*)d_in[1];  // [64, 68]
    const float* C = (const float*)d_in[2];  // [64, 64]
    float* O = (float*)d_out;                // [65536, 64]
    float4* RT = (float4*)d_ws;              // 64*67 float4 = 68,608 B

    prep<<<NSPL, 128, 0, stream>>>(T, C, RT);
    dim3 grid(BATCH / TROWS, NSPL / TCOLS);  // (512, 4) = 2048 blocks, 8/CU resident
    bspline_main<<<grid, NTHR, 0, stream>>>(X, T, RT, O);
}